// Round 5
// baseline (715.617 us; speedup 1.0000x reference)
//
#include <hip/hip_runtime.h>
#include <math.h>

#define BB 8
#define LL 2500
#define VV 50000
#define EE 100
#define FF 50
#define CC 8921
#define KK 10
#define PADW 5
#define LOUT 2501        // L + 2*PAD - K + 1
#define NLT 157          // ceil(LOUT/16)
#define LPAD (NLT * 16)  // 2512
#define NCT 140          // ceil(CC/64)
#define NT16 (NCT * 4)   // 560 16-c tiles
#define SROW 260         // staging row pitch (floats), 16B-aligned, 65*16B

typedef __attribute__((ext_vector_type(8))) short bf16x8;
typedef __attribute__((ext_vector_type(4))) float f32x4;

__device__ __forceinline__ short to_bf16(float f) {
  unsigned u = __builtin_bit_cast(unsigned, f);
  u += 0x7FFFu + ((u >> 16) & 1u);  // RNE
  return (short)(u >> 16);
}

// ---------------------------------------------------------------------------
// K1: embedding + conv1d + bias + tanh -> Z16 (B, LPAD, 64) bf16 row-major
// ---------------------------------------------------------------------------
__global__ void k1_conv(const int* __restrict__ text,
                        const float* __restrict__ embed,
                        const float* __restrict__ convw,
                        const float* __restrict__ convb,
                        short* __restrict__ Z16) {
  __shared__ float xw[73 * 101];
  const int b   = blockIdx.y;
  const int l0  = blockIdx.x * 64;
  const int tid = threadIdx.x;

  for (int idx = tid; idx < 73 * 100; idx += 256) {
    int r = idx / 100;
    int e = idx - r * 100;
    int t = l0 - PADW + r;
    float v = 0.f;
    if (t >= 0 && t < LL) {
      int tok = text[b * LL + t];
      v = embed[tok * EE + e];
    }
    xw[r * 101 + e] = v;
  }
  __syncthreads();

  const int ll = tid & 63;
  const int fg = __builtin_amdgcn_readfirstlane(tid >> 6);
  const int l  = l0 + ll;

  float acc[13];
#pragma unroll
  for (int j = 0; j < 13; ++j) {
    int f = fg + 4 * j;
    acc[j] = (f < FF) ? convb[f] : 0.f;
  }

  for (int e = 0; e < EE; ++e) {
    float xk[KK];
#pragma unroll
    for (int k = 0; k < KK; ++k) xk[k] = xw[(ll + k) * 101 + e];
#pragma unroll
    for (int j = 0; j < 13; ++j) {
      int f = fg + 4 * j;
      if (f < FF) {
        const float* wp = convw + (f * EE + e) * KK;
#pragma unroll
        for (int k = 0; k < KK; ++k) acc[j] += xk[k] * wp[k];
      }
    }
  }

  if (l < LPAD) {
#pragma unroll
    for (int j = 0; j < 13; ++j) {
      int f = fg + 4 * j;
      if (f < FF) {
        float v = (l < LOUT) ? tanhf(acc[j]) : 0.f;
        Z16[((size_t)b * LPAD + l) * 64 + f] = to_bf16(v);
      }
    }
  }
  for (int idx = tid; idx < 64 * 14; idx += 256) {
    int r = idx / 14, k = 50 + idx % 14;
    int lz = l0 + r;
    if (lz < LPAD) Z16[((size_t)b * LPAD + lz) * 64 + k] = 0;
  }
}

// ---------------------------------------------------------------------------
// Pack Qw / out_w (C,F) fp32 -> frag layout bf16 [t16][kh][lane][8]
// ---------------------------------------------------------------------------
__global__ void k_packW(const float* __restrict__ W, short* __restrict__ Wp) {
  int u = blockIdx.x * 256 + threadIdx.x;  // < NT16*2*64
  int lane = u & 63, kh = (u >> 6) & 1, t16 = u >> 7;
  int c  = t16 * 16 + (lane & 15);
  int k0 = 4 * (lane >> 4) + 32 * kh;
  union { short s[8]; uint4 v; } o;
#pragma unroll
  for (int j = 0; j < 8; ++j) {
    int k = k0 + (j & 3) + 16 * (j >> 2);
    float val = (c < CC && k < FF) ? W[c * FF + k] : 0.f;
    o.s[j] = to_bf16(val);
  }
  ((uint4*)Wp)[u] = o.v;
}

// ---------------------------------------------------------------------------
// Pack Z16 row-major -> frag layout bf16 [b][lt][kh][lane][8]
// ---------------------------------------------------------------------------
__global__ void k_packZ(const short* __restrict__ Z16, short* __restrict__ Zp) {
  int u = blockIdx.x * 256 + threadIdx.x;  // < B*NLT*2*64
  int lane = u & 63, kh = (u >> 6) & 1, t = u >> 7;
  int lt = t % NLT, b = t / NLT;
  int l  = lt * 16 + (lane & 15);
  int k0 = 4 * (lane >> 4) + 32 * kh;
  const short* src = Z16 + ((size_t)b * LPAD + l) * 64 + k0;
  uint2 a  = *(const uint2*)src;
  uint2 bb = *(const uint2*)(src + 16);
  uint4 o; o.x = a.x; o.y = a.y; o.z = bb.x; o.w = bb.y;
  ((uint4*)Zp)[u] = o;
}

// ---------------------------------------------------------------------------
// Fused attention v4: wave-per-mf.  Each wave owns 16 c-rows, walks all lt.
// Pass A: d = sum_l exp(s) (wave-local butterfly).  Pass B: recompute s,
// alpha -> LDS [16][256] chunks, drain 1KB-wide dwordx4 row stores; logits
// accumulated and written wave-locally.  No __syncthreads at all.
// Block id: b = id&7 (XCD-affine), ct = id>>3.
// ---------------------------------------------------------------------------
__global__ __launch_bounds__(256) void k_attn(
    const short* __restrict__ Zp, const short* __restrict__ Qp,
    const short* __restrict__ Op, const float* __restrict__ outb,
    float* __restrict__ alpha, float* __restrict__ logits) {
  const int id   = blockIdx.x;
  const int b    = id & 7;
  const int ct   = id >> 3;
  const int tid  = threadIdx.x;
  const int w    = tid >> 6;       // wave = mf index
  const int lane = tid & 63;
  const int g    = lane >> 4, col = lane & 15;
  const int crow = ct * 64 + w * 16;  // this wave's first c row

  __shared__ float sA[4 * 16 * SROW];  // per-wave [16 c][SROW] staging
  float* sAw = sA + w * (16 * SROW);

  // this wave's A-fragments (Qw and out_w), 16 c rows
  bf16x8 qf0, qf1, of0, of1;
  {
    int t16 = ct * 4 + w;
    qf0 = ((const bf16x8*)Qp)[(t16 * 2 + 0) * 64 + lane];
    qf1 = ((const bf16x8*)Qp)[(t16 * 2 + 1) * 64 + lane];
    of0 = ((const bf16x8*)Op)[(t16 * 2 + 0) * 64 + lane];
    of1 = ((const bf16x8*)Op)[(t16 * 2 + 1) * 64 + lane];
  }
  const bf16x8* Zb = (const bf16x8*)Zp + (size_t)b * NLT * 2 * 64;

  // ---- pass A: d = sum_l exp(s) ----
  float dacc[4] = {0.f, 0.f, 0.f, 0.f};
  {
    bf16x8 zc0, zc1, zn0, zn1;
    zn0 = Zb[0 * 64 + lane];
    zn1 = Zb[1 * 64 + lane];
    for (int lt = 0; lt < NLT; ++lt) {
      zc0 = zn0; zc1 = zn1;
      if (lt + 1 < NLT) {
        zn0 = Zb[((lt + 1) * 2 + 0) * 64 + lane];
        zn1 = Zb[((lt + 1) * 2 + 1) * 64 + lane];
      }
      const int   l    = lt * 16 + col;
      const float lmsk = (l < LOUT) ? 1.f : 0.f;
      f32x4 s = {0.f, 0.f, 0.f, 0.f};
      s = __builtin_amdgcn_mfma_f32_16x16x32_bf16(qf0, zc0, s, 0, 0, 0);
      s = __builtin_amdgcn_mfma_f32_16x16x32_bf16(qf1, zc1, s, 0, 0, 0);
#pragma unroll
      for (int r = 0; r < 4; ++r) dacc[r] += lmsk * __expf(s[r]);
    }
  }
  // butterfly over the 16 cols (within 16-lane groups)
  float rd[4];
#pragma unroll
  for (int r = 0; r < 4; ++r) {
    float v = dacc[r];
    v += __shfl_xor(v, 1); v += __shfl_xor(v, 2);
    v += __shfl_xor(v, 4); v += __shfl_xor(v, 8);
    rd[r] = 1.f / v;
  }

  // ---- pass B ----
  float lacc[4] = {0.f, 0.f, 0.f, 0.f};
  {
    bf16x8 zc0, zc1, zn0, zn1;
    zn0 = Zb[0 * 64 + lane];
    zn1 = Zb[1 * 64 + lane];
    for (int lt = 0; lt < NLT; ++lt) {
      zc0 = zn0; zc1 = zn1;
      if (lt + 1 < NLT) {
        zn0 = Zb[((lt + 1) * 2 + 0) * 64 + lane];
        zn1 = Zb[((lt + 1) * 2 + 1) * 64 + lane];
      }
      f32x4 s = {0.f, 0.f, 0.f, 0.f}, tt = {0.f, 0.f, 0.f, 0.f};
      s  = __builtin_amdgcn_mfma_f32_16x16x32_bf16(qf0, zc0, s, 0, 0, 0);
      s  = __builtin_amdgcn_mfma_f32_16x16x32_bf16(qf1, zc1, s, 0, 0, 0);
      tt = __builtin_amdgcn_mfma_f32_16x16x32_bf16(of0, zc0, tt, 0, 0, 0);
      tt = __builtin_amdgcn_mfma_f32_16x16x32_bf16(of1, zc1, tt, 0, 0, 0);
      const int l = lt * 16 + col;
#pragma unroll
      for (int r = 0; r < 4; ++r) {
        float a = __expf(s[r]) * rd[r];
        lacc[r] += (l < LOUT) ? a * tt[r] : 0.f;
        sAw[(g * 4 + r) * SROW + (lt & 15) * 16 + col] = a;
      }
      // drain a completed 16c x 256l chunk as 1KB-wide row stores
      if ((lt & 15) == 15 || lt == NLT - 1) {
        const int l0  = (lt & ~15) * 16;
        int rem = LOUT - l0; if (rem > 256) rem = 256;
        const int i4 = 4 * lane;
#pragma unroll 4
        for (int rr = 0; rr < 16; ++rr) {
          int c = crow + rr;
          if (c < CC) {
            float* dst = alpha + (size_t)((size_t)b * CC + c) * LOUT + l0;
            const float* src = sAw + rr * SROW;
            if (i4 + 4 <= rem) {
              *(float4*)(dst + i4) = *(const float4*)(src + i4);
            } else if (i4 < rem) {
#pragma unroll
              for (int j = 0; j < 4; ++j)
                if (i4 + j < rem) dst[i4 + j] = src[i4 + j];
            }
          }
        }
      }
    }
  }

  // logits: butterfly over 16 cols, then group-leader writes 4 rows
#pragma unroll
  for (int r = 0; r < 4; ++r) {
    float v = lacc[r];
    v += __shfl_xor(v, 1); v += __shfl_xor(v, 2);
    v += __shfl_xor(v, 4); v += __shfl_xor(v, 8);
    lacc[r] = v;
  }
  if (col == 0) {
#pragma unroll
    for (int r = 0; r < 4; ++r) {
      int c = crow + g * 4 + r;
      if (c < CC) logits[b * CC + c] = lacc[r] + outb[c];
    }
  }
}

// ---------------------------------------------------------------------------
extern "C" void kernel_launch(void* const* d_in, const int* in_sizes, int n_in,
                              void* d_out, int out_size, void* d_ws, size_t ws_size,
                              hipStream_t stream) {
  const int*   text  = (const int*)d_in[0];
  const float* embed = (const float*)d_in[1];
  const float* convw = (const float*)d_in[2];
  const float* convb = (const float*)d_in[3];
  const float* Qw    = (const float*)d_in[4];
  const float* outw  = (const float*)d_in[5];
  const float* outb  = (const float*)d_in[6];

  float* out    = (float*)d_out;
  float* logits = out;
  float* alpha  = out + (size_t)BB * CC;

  short* Z16 = (short*)alpha;  // staging; fully overwritten by k_attn

  short* wsS = (short*)d_ws;
  short* Zp  = wsS;
  short* Qp  = Zp + (size_t)BB * NLT * 2 * 64 * 8;
  short* Op  = Qp + (size_t)NT16 * 2 * 64 * 8;

  k1_conv<<<dim3((LPAD + 63) / 64, BB), 256, 0, stream>>>(
      text, embed, convw, convb, Z16);
  k_packW<<<(NT16 * 128) / 256, 256, 0, stream>>>(Qw, Qp);
  k_packW<<<(NT16 * 128) / 256, 256, 0, stream>>>(outw, Op);
  k_packZ<<<(BB * NLT * 128) / 256, 256, 0, stream>>>(Z16, Zp);
  k_attn<<<dim3(NCT * BB), 256, 0, stream>>>(Zp, Qp, Op, outb, alpha, logits);
}

// Round 6
// 672.538 us; speedup vs baseline: 1.0641x; 1.0641x over previous
//
#include <hip/hip_runtime.h>
#include <math.h>

#define BB 8
#define LL 2500
#define VV 50000
#define EE 100
#define FF 50
#define CC 8921
#define KK 10
#define PADW 5
#define LOUT 2501        // L + 2*PAD - K + 1
#define NLT 157          // ceil(LOUT/16)
#define LPAD (NLT * 16)  // 2512
#define NCT 140          // ceil(CC/64)
#define NT16 (NCT * 4)   // 560 16-c tiles
#define NG 10            // lt groups of 16 (4 contiguous per wave)

typedef __attribute__((ext_vector_type(8))) short bf16x8;
typedef __attribute__((ext_vector_type(4))) float f32x4;

__device__ __forceinline__ short to_bf16(float f) {
  unsigned u = __builtin_bit_cast(unsigned, f);
  u += 0x7FFFu + ((u >> 16) & 1u);  // RNE
  return (short)(u >> 16);
}

// ---------------------------------------------------------------------------
// K1: embedding + conv1d + bias + tanh -> Zp directly in MFMA frag layout
// [b][lt][kh][lane][8] bf16 (k 50..63 zero, l >= LOUT zero), via LDS
// transpose.  grid (40, B), block 256 (wave w handles f = w + 4*j).
// ---------------------------------------------------------------------------
__global__ void k1_conv(const int* __restrict__ text,
                        const float* __restrict__ embed,
                        const float* __restrict__ convw,
                        const float* __restrict__ convb,
                        short* __restrict__ Zp) {
  __shared__ float xw[73 * 101];
  __shared__ short zt[64][72];  // 64 l-rows x 64 k (pad 72)
  const int b   = blockIdx.y;
  const int l0  = blockIdx.x * 64;
  const int tid = threadIdx.x;

  // zero zt (covers k=50..63 pad lanes)
  for (int i = tid; i < 64 * 72 / 2; i += 256) ((int*)zt)[i] = 0;

  // stage embedding window rows t = l0-5 .. l0+67
  for (int idx = tid; idx < 73 * 100; idx += 256) {
    int r = idx / 100;
    int e = idx - r * 100;
    int t = l0 - PADW + r;
    float v = 0.f;
    if (t >= 0 && t < LL) {
      int tok = text[b * LL + t];
      v = embed[tok * EE + e];
    }
    xw[r * 101 + e] = v;
  }
  __syncthreads();

  const int ll = tid & 63;
  const int fg = __builtin_amdgcn_readfirstlane(tid >> 6);
  const int l  = l0 + ll;

  float acc[13];
#pragma unroll
  for (int j = 0; j < 13; ++j) {
    int f = fg + 4 * j;
    acc[j] = (f < FF) ? convb[f] : 0.f;
  }

  for (int e = 0; e < EE; ++e) {
    float xk[KK];
#pragma unroll
    for (int k = 0; k < KK; ++k) xk[k] = xw[(ll + k) * 101 + e];
#pragma unroll
    for (int j = 0; j < 13; ++j) {
      int f = fg + 4 * j;
      if (f < FF) {
        const float* wp = convw + (f * EE + e) * KK;
#pragma unroll
        for (int k = 0; k < KK; ++k) acc[j] += xk[k] * wp[k];
      }
    }
  }

#pragma unroll
  for (int j = 0; j < 13; ++j) {
    int f = fg + 4 * j;
    if (f < FF) {
      float v = (l < LOUT) ? tanhf(acc[j]) : 0.f;
      zt[ll][f] = to_bf16(v);
    }
  }
  __syncthreads();

  // transpose-out: 8 frag rows (i=0..3, kh=0..1), 64 lanes each
#pragma unroll
  for (int p = 0; p < 2; ++p) {
    int u    = tid + 256 * p;          // 0..511
    int lane = u & 63, kh = (u >> 6) & 1, i = u >> 7;
    int lt   = blockIdx.x * 4 + i;
    if (lt < NLT) {
      int lrow = i * 16 + (lane & 15);
      int k0   = 4 * (lane >> 4) + 32 * kh;
      uint2 a  = *(const uint2*)&zt[lrow][k0];
      uint2 b2 = *(const uint2*)&zt[lrow][k0 + 16];
      uint4 o; o.x = a.x; o.y = a.y; o.z = b2.x; o.w = b2.y;
      ((uint4*)Zp)[((size_t)b * NLT + lt) * 2 * 64 + kh * 64 + lane] = o;
    }
  }
}

// ---------------------------------------------------------------------------
// Pack Qw / out_w (C,F) fp32 -> frag layout bf16 [t16][kh][lane][8]
// ---------------------------------------------------------------------------
__global__ void k_packW(const float* __restrict__ W, short* __restrict__ Wp) {
  int u = blockIdx.x * 256 + threadIdx.x;  // < NT16*2*64
  int lane = u & 63, kh = (u >> 6) & 1, t16 = u >> 7;
  int c  = t16 * 16 + (lane & 15);
  int k0 = 4 * (lane >> 4) + 32 * kh;
  union { short s[8]; uint4 v; } o;
#pragma unroll
  for (int j = 0; j < 8; ++j) {
    int k = k0 + (j & 3) + 16 * (j >> 2);
    float val = (c < CC && k < FF) ? W[c * FF + k] : 0.f;
    o.s[j] = to_bf16(val);
  }
  ((uint4*)Wp)[u] = o.v;
}

// ---------------------------------------------------------------------------
// Fused attention (R2 structure + nt stores). Pass A: d = sum_l exp(s).
// Pass B: recompute s, stage 16c x 64l per wave in LDS, drain 256B rows
// with nontemporal stores; fused logits.  b = id&7 (XCD-affine), ct = id>>3.
// ---------------------------------------------------------------------------
__global__ __launch_bounds__(256) void k_attn(
    const short* __restrict__ Zp, const short* __restrict__ Qp,
    const short* __restrict__ Op, const float* __restrict__ outb,
    float* __restrict__ alpha, float* __restrict__ logits) {
  const int id   = blockIdx.x;
  const int b    = id & 7;
  const int ct   = id >> 3;
  const int tid  = threadIdx.x;
  const int w    = tid >> 6;
  const int lane = tid & 63;
  const int g    = lane >> 4, col = lane & 15;
  const int cb   = ct * 64;

  __shared__ float red[4][4][4][4];  // [w][mf][g][r]
  __shared__ float rdinv[64];
  __shared__ float sA[4 * 16 * 68];  // per-wave [16 c][68] staging

  bf16x8 qf[4][2], of[4][2];
#pragma unroll
  for (int mf = 0; mf < 4; ++mf)
#pragma unroll
    for (int kh = 0; kh < 2; ++kh) {
      int t16 = ct * 4 + mf;
      qf[mf][kh] = ((const bf16x8*)Qp)[(t16 * 2 + kh) * 64 + lane];
      of[mf][kh] = ((const bf16x8*)Op)[(t16 * 2 + kh) * 64 + lane];
    }
  const bf16x8* Zb = (const bf16x8*)Zp + (size_t)b * NLT * 2 * 64;

  float dacc[4][4];
#pragma unroll
  for (int mf = 0; mf < 4; ++mf)
#pragma unroll
    for (int r = 0; r < 4; ++r) dacc[mf][r] = 0.f;

  // ---- pass A ----
  for (int t = 0; t < NG; ++t) {
    const int lt0 = t * 16 + w * 4;
    bf16x8 zz[4][2];
#pragma unroll
    for (int i = 0; i < 4; ++i) {
      int lt = lt0 + i; if (lt > NLT - 1) lt = NLT - 1;
      zz[i][0] = Zb[(lt * 2 + 0) * 64 + lane];
      zz[i][1] = Zb[(lt * 2 + 1) * 64 + lane];
    }
#pragma unroll
    for (int i = 0; i < 4; ++i) {
      int   l    = (lt0 + i) * 16 + col;  // unclamped: masks dups + tail
      float lmsk = (l < LOUT) ? 1.f : 0.f;
#pragma unroll
      for (int mf = 0; mf < 4; ++mf) {
        f32x4 acc = {0.f, 0.f, 0.f, 0.f};
        acc = __builtin_amdgcn_mfma_f32_16x16x32_bf16(qf[mf][0], zz[i][0], acc, 0, 0, 0);
        acc = __builtin_amdgcn_mfma_f32_16x16x32_bf16(qf[mf][1], zz[i][1], acc, 0, 0, 0);
#pragma unroll
        for (int r = 0; r < 4; ++r) dacc[mf][r] += lmsk * __expf(acc[r]);
      }
    }
  }

  // reduce d: 16-col butterfly then cross-wave via LDS
#pragma unroll
  for (int mf = 0; mf < 4; ++mf)
#pragma unroll
    for (int r = 0; r < 4; ++r) {
      float v = dacc[mf][r];
      v += __shfl_xor(v, 1); v += __shfl_xor(v, 2);
      v += __shfl_xor(v, 4); v += __shfl_xor(v, 8);
      dacc[mf][r] = v;
    }
  if (col == 0)
#pragma unroll
    for (int mf = 0; mf < 4; ++mf)
#pragma unroll
      for (int r = 0; r < 4; ++r) red[w][mf][g][r] = dacc[mf][r];
  __syncthreads();
  if (tid < 64) {
    int mf = tid >> 4, gg = (tid >> 2) & 3, r = tid & 3;
    float s = red[0][mf][gg][r] + red[1][mf][gg][r] +
              red[2][mf][gg][r] + red[3][mf][gg][r];
    rdinv[tid] = 1.f / s;
  }
  __syncthreads();

  float rd[4][4];
#pragma unroll
  for (int mf = 0; mf < 4; ++mf)
#pragma unroll
    for (int r = 0; r < 4; ++r) rd[mf][r] = rdinv[mf * 16 + g * 4 + r];

  float lacc[4][4];
#pragma unroll
  for (int mf = 0; mf < 4; ++mf)
#pragma unroll
    for (int r = 0; r < 4; ++r) lacc[mf][r] = 0.f;

  float* sAw = sA + w * (16 * 68);

  // ---- pass B ----
  for (int t = 0; t < NG; ++t) {
    const int lt0 = t * 16 + w * 4;
    bf16x8 zz[4][2];
#pragma unroll
    for (int i = 0; i < 4; ++i) {
      int lt = lt0 + i; if (lt > NLT - 1) lt = NLT - 1;
      zz[i][0] = Zb[(lt * 2 + 0) * 64 + lane];
      zz[i][1] = Zb[(lt * 2 + 1) * 64 + lane];
    }
#pragma unroll
    for (int mf = 0; mf < 4; ++mf) {
#pragma unroll
      for (int i = 0; i < 4; ++i) {
        f32x4 s = {0.f, 0.f, 0.f, 0.f}, tt = {0.f, 0.f, 0.f, 0.f};
        s  = __builtin_amdgcn_mfma_f32_16x16x32_bf16(qf[mf][0], zz[i][0], s, 0, 0, 0);
        s  = __builtin_amdgcn_mfma_f32_16x16x32_bf16(qf[mf][1], zz[i][1], s, 0, 0, 0);
        tt = __builtin_amdgcn_mfma_f32_16x16x32_bf16(of[mf][0], zz[i][0], tt, 0, 0, 0);
        tt = __builtin_amdgcn_mfma_f32_16x16x32_bf16(of[mf][1], zz[i][1], tt, 0, 0, 0);
        int l = (lt0 + i) * 16 + col;
#pragma unroll
        for (int r = 0; r < 4; ++r) {
          float a = __expf(s[r]) * rd[mf][r];
          lacc[mf][r] += (l < LOUT) ? a * tt[r] : 0.f;
          sAw[(g * 4 + r) * 68 + i * 16 + col] = a;
        }
      }
      // drain: 16 rows x 64 contiguous floats (256B per wave-store), nt
      const int l0w = lt0 * 16;
      const int lw  = l0w + lane;
#pragma unroll
      for (int rr = 0; rr < 16; ++rr) {
        int c = cb + mf * 16 + rr;
        if (lw < LOUT && c < CC)
          __builtin_nontemporal_store(
              sAw[rr * 68 + lane],
              &alpha[(size_t)(b * CC + c) * LOUT + lw]);
      }
    }
  }

  // logits reduction
#pragma unroll
  for (int mf = 0; mf < 4; ++mf)
#pragma unroll
    for (int r = 0; r < 4; ++r) {
      float v = lacc[mf][r];
      v += __shfl_xor(v, 1); v += __shfl_xor(v, 2);
      v += __shfl_xor(v, 4); v += __shfl_xor(v, 8);
      lacc[mf][r] = v;
    }
  __syncthreads();
  if (col == 0)
#pragma unroll
    for (int mf = 0; mf < 4; ++mf)
#pragma unroll
      for (int r = 0; r < 4; ++r) red[w][mf][g][r] = lacc[mf][r];
  __syncthreads();
  if (tid < 64) {
    int mf = tid >> 4, gg = (tid >> 2) & 3, r = tid & 3;
    int c = cb + tid;
    if (c < CC) {
      float v = red[0][mf][gg][r] + red[1][mf][gg][r] +
                red[2][mf][gg][r] + red[3][mf][gg][r];
      logits[b * CC + c] = v + outb[c];
    }
  }
}

// ---------------------------------------------------------------------------
extern "C" void kernel_launch(void* const* d_in, const int* in_sizes, int n_in,
                              void* d_out, int out_size, void* d_ws, size_t ws_size,
                              hipStream_t stream) {
  const int*   text  = (const int*)d_in[0];
  const float* embed = (const float*)d_in[1];
  const float* convw = (const float*)d_in[2];
  const float* convb = (const float*)d_in[3];
  const float* Qw    = (const float*)d_in[4];
  const float* outw  = (const float*)d_in[5];
  const float* outb  = (const float*)d_in[6];

  float* out    = (float*)d_out;
  float* logits = out;
  float* alpha  = out + (size_t)BB * CC;

  short* wsS = (short*)d_ws;
  short* Zp  = wsS;                                 // B*NLT*2*64*8 shorts
  short* Qp  = Zp + (size_t)BB * NLT * 2 * 64 * 8;  // NT16*2*64*8
  short* Op  = Qp + (size_t)NT16 * 2 * 64 * 8;

  k1_conv<<<dim3(40, BB), 256, 0, stream>>>(text, embed, convw, convb, Zp);
  k_packW<<<(NT16 * 128) / 256, 256, 0, stream>>>(Qw, Qp);
  k_packW<<<(NT16 * 128) / 256, 256, 0, stream>>>(outw, Op);
  k_attn<<<dim3(NCT * BB), 256, 0, stream>>>(Zp, Qp, Op, outb, alpha, logits);
}